// Round 1
// baseline (803.737 us; speedup 1.0000x reference)
//
#include <hip/hip_runtime.h>

#define B 32
#define F 1024
#define S 2048
#define KTOP 16
#define CHUNKS 16
#define ROWS_PER_CHUNK (S / CHUNKS) /* 128 */

// Kernel A: partial column sums of w over row-chunks.
// Each block: 256 threads * float4 = 1024 columns; grid = B * (S/1024) * CHUNKS.
__global__ void colsum_partial(const float* __restrict__ w, float* __restrict__ partial) {
    int bid = blockIdx.x;
    int chunk = bid % CHUNKS;
    int cg = (bid / CHUNKS) % (S / 1024);
    int b = bid / (CHUNKS * (S / 1024));
    int col = cg * 1024 + threadIdx.x * 4;
    size_t base = (size_t)b * S * S + (size_t)chunk * ROWS_PER_CHUNK * S + col;
    float4 acc = make_float4(0.f, 0.f, 0.f, 0.f);
#pragma unroll 4
    for (int i = 0; i < ROWS_PER_CHUNK; ++i) {
        float4 v = *(const float4*)(w + base + (size_t)i * S);
        acc.x += v.x; acc.y += v.y; acc.z += v.z; acc.w += v.w;
    }
    *(float4*)(partial + (size_t)(b * CHUNKS + chunk) * S + col) = acc;
}

// Kernel B: fold CHUNKS partials -> column sums [B][S].
__global__ void colsum_reduce(const float* __restrict__ partial, float* __restrict__ sums) {
    int t = blockIdx.x * blockDim.x + threadIdx.x; // 0 .. B*S-1
    int b = t / S;
    int s = t % S;
    float acc = 0.f;
#pragma unroll
    for (int c = 0; c < CHUNKS; ++c) acc += partial[(size_t)(b * CHUNKS + c) * S + s];
    sums[t] = acc;
}

// Kernel C: top-16 per batch, descending, ties -> lower index (lax.top_k semantics).
__global__ void topk_kernel(const float* __restrict__ sums, int* __restrict__ idx) {
    __shared__ float vals[S];
    __shared__ float rv[256];
    __shared__ int ri[256];
    int b = blockIdx.x;
    int tid = threadIdx.x;
    for (int s = tid; s < S; s += 256) vals[s] = sums[b * S + s];
    __syncthreads();
    for (int k = 0; k < KTOP; ++k) {
        float bv = -1e30f;
        int bi = 0x7fffffff;
        for (int s = tid; s < S; s += 256) {
            float v = vals[s];
            if (v > bv) { bv = v; bi = s; } // strict > keeps smallest index per thread
        }
        rv[tid] = bv; ri[tid] = bi;
        __syncthreads();
        for (int off = 128; off > 0; off >>= 1) {
            if (tid < off) {
                float ov = rv[tid + off]; int oi = ri[tid + off];
                if (ov > rv[tid] || (ov == rv[tid] && oi < ri[tid])) { rv[tid] = ov; ri[tid] = oi; }
            }
            __syncthreads();
        }
        if (tid == 0) {
            idx[b * KTOP + k] = ri[0];
            vals[ri[0]] = -1e30f;
        }
        __syncthreads();
    }
}

// Kernel D: out[b][f][k] = x[b][f][idx[b][k]]. Coalesced writes; scattered reads via L2.
__global__ void gather_kernel(const float* __restrict__ x, const int* __restrict__ idx,
                              float* __restrict__ out) {
    int t = blockIdx.x * blockDim.x + threadIdx.x; // 0 .. B*F*KTOP-1
    int k = t % KTOP;
    int f = (t / KTOP) % F;
    int b = t / (KTOP * F);
    int j = idx[b * KTOP + k];
    out[t] = x[((size_t)b * F + f) * S + j];
}

extern "C" void kernel_launch(void* const* d_in, const int* in_sizes, int n_in,
                              void* d_out, int out_size, void* d_ws, size_t ws_size,
                              hipStream_t stream) {
    const float* x = (const float*)d_in[0];
    const float* w = (const float*)d_in[1];
    float* out = (float*)d_out;

    float* partial = (float*)d_ws;                       // B*CHUNKS*S floats = 4 MiB
    float* sums = partial + (size_t)B * CHUNKS * S;      // B*S floats = 256 KiB
    int* idx = (int*)(sums + (size_t)B * S);             // B*KTOP ints = 2 KiB

    colsum_partial<<<B * (S / 1024) * CHUNKS, 256, 0, stream>>>(w, partial);
    colsum_reduce<<<(B * S) / 256, 256, 0, stream>>>(partial, sums);
    topk_kernel<<<B, 256, 0, stream>>>(sums, idx);
    gather_kernel<<<(B * F * KTOP) / 256, 256, 0, stream>>>(x, idx, out);
}